// Round 11
// baseline (61.552 us; speedup 1.0000x reference)
//
#include <hip/hip_runtime.h>
#include <hip/hip_bf16.h>
#include <math.h>

// ---- problem constants ----
#define SS 2304       // S = B*C*K*K
#define QSCALE 0.8329506128860126f  // log2(e)/sqrt(3)
#define TSPLIT 3
#define TCH 768       // SS / TSPLIT
#define SCH 9         // s-chunks of 256 rows
// grid = 36*9*3 = 972 blocks x 8 waves: single co-resident pass (<=1024)

// LDS layout (ushort idx):
//   K   [0,    3072)  768 tok * 4
//   V^T [3072, 6176)  4 rows, stride 776 (768 + 8 pad)
//   Q   [6176, 7200)  256 rows * 4
//   fw  [7200, 8994)  897 floats: ce+pe_n [0,768) | Wq/Wk/Wv [780,888) | b [888,897)
#define LK 0
#define LV 3072
#define LVS 776
#define LQ 6176
#define LF 7200

typedef short s8v __attribute__((ext_vector_type(8)));
typedef float f32x16 __attribute__((ext_vector_type(16)));
typedef float f32x2 __attribute__((ext_vector_type(2)));

static __device__ __forceinline__ unsigned short f2b(float f) {
  __hip_bfloat16 h = __float2bfloat16(f);
  return __builtin_bit_cast(unsigned short, h);
}

// packed exp2: 2 elements via v_pk_fma_f32 (full-rate VALU) instead of the
// 1/4-rate trans pipe. deg-4 poly on f in [-0.5,0.5], rel err <= 4.2e-5
// (bf16 P quantization is 4e-3 -> poly error invisible downstream).
static __device__ __forceinline__ f32x2 exp2v2(f32x2 x) {
  f32x2 n;
  n.x = __builtin_rintf(x.x);          // v_rndne_f32
  n.y = __builtin_rintf(x.y);
  const f32x2 f = x - n;               // v_pk_add_f32
  f32x2 p = __builtin_elementwise_fma(f, (f32x2)0.009618129107f,
                                      (f32x2)0.055504108664f);
  p = __builtin_elementwise_fma(f, p, (f32x2)0.240226506959f);
  p = __builtin_elementwise_fma(f, p, (f32x2)0.693147180560f);
  p = __builtin_elementwise_fma(f, p, (f32x2)1.0f);
  f32x2 r;
  r.x = ldexpf(p.x, (int)n.x);         // v_cvt_i32_f32 + v_ldexp_f32
  r.y = ldexpf(p.y, (int)n.y);
  return r;
}

// ============================================================
// K2': fused embed+QKV+flash-attention partials.
// block = (nh, schunk of 256 s, tc of 768 t); 972 blocks x 512 thr.
// part[(nh*TSPLIT+tc)*SS + s] = float4(o0,o1,o2,sum_exp) unnormalized.
// ============================================================
__global__ __launch_bounds__(512) void k2_fused(
    const float* __restrict__ x, const float* __restrict__ ce,
    const float* __restrict__ pe, const float* __restrict__ ipw,
    const float* __restrict__ ipb, float4* __restrict__ part) {
  __shared__ __align__(16) unsigned short lds[8994];
  float* fw = (float*)(lds + LF);       // byte 14400, 16B aligned
  const int tid = threadIdx.x;
  const int tc = blockIdx.x % TSPLIT;
  const int schunk = (blockIdx.x / TSPLIT) % SCH;
  const int nh = blockIdx.x / (TSPLIT * SCH);
  const int n = nh >> 2, hh = nh & 3;
  const int t0 = tc * TCH;

  // ---- stage weights: ce+pe[n] folded, head-sliced W/b ----
  for (int i = tid; i < 768; i += 512) {
    const int e = i - (i / 12) * 12;
    fw[i] = ce[i] + pe[n * 12 + e];
  }
  if (tid < 108) {                      // Wq 780..816 | Wk 816..852 | Wv 852..888
    const int grp = tid / 36, idx = tid % 36;
    fw[780 + tid] = ipw[(grp * 12 + hh * 3 + idx / 12) * 12 + idx % 12];
  }
  if (tid >= 128 && tid < 137) {        // bq 888 | bk 891 | bv 894
    const int j = tid - 128;
    fw[888 + j] = ipb[(j / 3) * 12 + hh * 3 + (j % 3)];
  }
  __syncthreads();

  // ---- embed K/V for this block's 768 tokens ----
  for (int tl = tid; tl < TCH; tl += 512) {
    const int tg = t0 + tl;
    const int pp = tg % 9, c = (tg / 9) % 64, b = tg / 576;
    const float val =
        x[((b * 64 + c) * 5 + (pp / 3 + n / 3)) * 5 + (pp % 3 + n % 3)];
    float sq[12];
#pragma unroll
    for (int e = 0; e < 12; ++e) sq[e] = fw[c * 12 + e] + val;
    float kd[3], vd[3];
#pragma unroll
    for (int d = 0; d < 3; ++d) {
      float a1 = fw[891 + d], a2 = fw[894 + d];
#pragma unroll
      for (int e = 0; e < 12; ++e) {
        a1 = fmaf(fw[816 + d * 12 + e], sq[e], a1);   // k
        a2 = fmaf(fw[852 + d * 12 + e], sq[e], a2);   // v
      }
      kd[d] = a1; vd[d] = a2;
    }
    ushort4 kk;
    kk.x = f2b(kd[0]); kk.y = f2b(kd[1]); kk.z = f2b(kd[2]); kk.w = 0;
    *(ushort4*)(lds + LK + tl * 4) = kk;
    lds[LV + 0 * LVS + tl] = f2b(vd[0]);
    lds[LV + 1 * LVS + tl] = f2b(vd[1]);
    lds[LV + 2 * LVS + tl] = f2b(vd[2]);
    lds[LV + 3 * LVS + tl] = 0x3F80;    // ones row -> sum_exp in acc[3]
  }

  // ---- embed Q for this block's 256 s-rows ----
  if (tid < 256) {
    const int s = schunk * 256 + tid;
    const int pp = s % 9, c = (s / 9) % 64, b = s / 576;
    const float val =
        x[((b * 64 + c) * 5 + (pp / 3 + n / 3)) * 5 + (pp % 3 + n % 3)];
    float sq[12];
#pragma unroll
    for (int e = 0; e < 12; ++e) sq[e] = fw[c * 12 + e] + val;
    float qd[3];
#pragma unroll
    for (int d = 0; d < 3; ++d) {
      float a = fw[888 + d];
#pragma unroll
      for (int e = 0; e < 12; ++e) a = fmaf(fw[780 + d * 12 + e], sq[e], a);
      qd[d] = a * QSCALE;
    }
    ushort4 qq;
    qq.x = f2b(qd[0]); qq.y = f2b(qd[1]); qq.z = f2b(qd[2]); qq.w = 0;
    *(ushort4*)(lds + LQ + tid * 4) = qq;
  }
  __syncthreads();

  // ---- MFMA flash attention over 24 t-tiles ----
  const int lane = tid & 63;
  const int wv = tid >> 6;              // 0..7
  const int h = lane >> 5;
  const int sl = lane & 31;
  const int s0 = schunk * 256 + wv * 32;

  union F { s8v v; unsigned int u[4]; };

  F fq;
  {
    const uint2 qw = *(const uint2*)(lds + LQ + (wv * 32 + sl) * 4);
    fq.u[0] = h ? 0u : qw.x;
    fq.u[1] = h ? 0u : qw.y;
    fq.u[2] = 0u;
    fq.u[3] = 0u;
  }

  // static per-lane bases; t-offsets compile-time (full unroll)
  const int kbase = LK + sl * 4;                       // h=1: dup read (x0 weight)
  const int vbase = LV + (sl & 3) * LVS + h * 8;       // rows>=4 -> unread acc rows

  const f32x16 kz = {};
  f32x16 acc = {};
#pragma unroll
  for (int t = 0; t < TCH / 32; ++t) {
    F fa;
    const uint2 kw = *(const uint2*)(lds + kbase + t * 128);
    fa.u[0] = kw.x; fa.u[1] = kw.y; fa.u[2] = 0u; fa.u[3] = 0u;
    f32x16 sT = __builtin_amdgcn_mfma_f32_32x32x16_bf16(fa.v, fq.v, kz, 0, 0, 0);

    // packed-poly exp2 on 8 float2 pairs, then pack to bf16 B-frags
    unsigned int c0, c1, c2, c3, d0, d1, d2, d3;
    {
      f32x2 r0 = exp2v2((f32x2){sT[0], sT[1]});
      f32x2 r1 = exp2v2((f32x2){sT[2], sT[3]});
      f32x2 r2 = exp2v2((f32x2){sT[4], sT[5]});
      f32x2 r3 = exp2v2((f32x2){sT[6], sT[7]});
      asm("v_cvt_pk_bf16_f32 %0, %1, %2" : "=v"(c0) : "v"(r0.x), "v"(r0.y));
      asm("v_cvt_pk_bf16_f32 %0, %1, %2" : "=v"(c1) : "v"(r1.x), "v"(r1.y));
      asm("v_cvt_pk_bf16_f32 %0, %1, %2" : "=v"(c2) : "v"(r2.x), "v"(r2.y));
      asm("v_cvt_pk_bf16_f32 %0, %1, %2" : "=v"(c3) : "v"(r3.x), "v"(r3.y));
    }
    {
      f32x2 r4 = exp2v2((f32x2){sT[8], sT[9]});
      f32x2 r5 = exp2v2((f32x2){sT[10], sT[11]});
      f32x2 r6 = exp2v2((f32x2){sT[12], sT[13]});
      f32x2 r7 = exp2v2((f32x2){sT[14], sT[15]});
      asm("v_cvt_pk_bf16_f32 %0, %1, %2" : "=v"(d0) : "v"(r4.x), "v"(r4.y));
      asm("v_cvt_pk_bf16_f32 %0, %1, %2" : "=v"(d1) : "v"(r5.x), "v"(r5.y));
      asm("v_cvt_pk_bf16_f32 %0, %1, %2" : "=v"(d2) : "v"(r6.x), "v"(r6.y));
      asm("v_cvt_pk_bf16_f32 %0, %1, %2" : "=v"(d3) : "v"(r7.x), "v"(r7.y));
    }
    asm("v_permlane32_swap_b32 %0, %1" : "+v"(c0), "+v"(c2));
    asm("v_permlane32_swap_b32 %0, %1" : "+v"(c1), "+v"(c3));
    asm("v_permlane32_swap_b32 %0, %1" : "+v"(d0), "+v"(d2));
    asm("v_permlane32_swap_b32 %0, %1" : "+v"(d1), "+v"(d3));
    F pb0; pb0.u[0] = c0; pb0.u[1] = c1; pb0.u[2] = c2; pb0.u[3] = c3;
    F pb1; pb1.u[0] = d0; pb1.u[1] = d1; pb1.u[2] = d2; pb1.u[3] = d3;

    F fv0, fv1;
    *(uint4*)fv0.u = *(const uint4*)(lds + vbase + t * 32);
    *(uint4*)fv1.u = *(const uint4*)(lds + vbase + t * 32 + 16);
    acc = __builtin_amdgcn_mfma_f32_32x32x16_bf16(fv0.v, pb0.v, acc, 0, 0, 0);
    acc = __builtin_amdgcn_mfma_f32_32x32x16_bf16(fv1.v, pb1.v, acc, 0, 0, 0);
  }

  if (h == 0) {
    part[((size_t)(nh * TSPLIT + tc)) * SS + s0 + sl] =
        make_float4(acc[0], acc[1], acc[2], acc[3]);
  }
}

// ============================================================
// K3: combine partials -> ctx; out_proj; +seq; LN1; FF; LN2; linear; FOLD.
// block = one (b,c) pair: 81 tokens, 128 threads; 256 blocks.
// ============================================================
__global__ __launch_bounds__(128) void k3_mlp_fold(
    const float4* __restrict__ part, const float* __restrict__ x,
    const float* __restrict__ ce, const float* __restrict__ pe,
    const float* __restrict__ opw, const float* __restrict__ opb,
    const float* __restrict__ ln1w, const float* __restrict__ ln1b,
    const float* __restrict__ f1w, const float* __restrict__ f1b,
    const float* __restrict__ f2w, const float* __restrict__ f2b,
    const float* __restrict__ ln2w, const float* __restrict__ ln2b,
    const float* __restrict__ linw, const float* __restrict__ linb,
    float* __restrict__ out) {
  __shared__ float L[828];
  __shared__ float pvs[81];
  const int tid = threadIdx.x;
  for (int i = tid; i < 144; i += 128) L[i] = opw[i];
  for (int i = tid; i < 288; i += 128) {
    L[180 + i] = f1w[i];
    L[492 + i] = f2w[i];
  }
  if (tid < 12) {
    L[144 + tid] = opb[tid];
    L[156 + tid] = ln1w[tid];
    L[168 + tid] = ln1b[tid];
    L[780 + tid] = f2b[tid];
    L[792 + tid] = ln2w[tid];
    L[804 + tid] = ln2b[tid];
    L[816 + tid] = linw[tid];
  }
  if (tid < 24) L[468 + tid] = f1b[tid];
  __syncthreads();

  const int bc = blockIdx.x;             // b*64 + c
  const int c = bc & 63;

  if (tid < 81) {
    const int n = tid / 9;
    const int p = tid % 9;
    const int s = bc * 9 + p;
    const int pi = p / 3, pj = p % 3;
    const int hi = n / 3, wj = n % 3;
    const float val = x[(bc * 5 + (pi + hi)) * 5 + (pj + wj)];

    float ctx[12];
#pragma unroll
    for (int h = 0; h < 4; ++h) {
      const float4* pp = part + ((size_t)((n * 4 + h) * TSPLIT)) * SS + s;
      float l = 0.f, a0 = 0.f, a1 = 0.f, a2 = 0.f;
#pragma unroll
      for (int t = 0; t < TSPLIT; ++t) {
        const float4 v = pp[(size_t)t * SS];
        a0 += v.x; a1 += v.y; a2 += v.z; l += v.w;
      }
      const float rl = 1.0f / l;
      ctx[h * 3 + 0] = a0 * rl;
      ctx[h * 3 + 1] = a1 * rl;
      ctx[h * 3 + 2] = a2 * rl;
    }

    float x1[12];
#pragma unroll
    for (int e = 0; e < 12; ++e) {
      float acc = L[144 + e];
#pragma unroll
      for (int j = 0; j < 12; ++j) acc = fmaf(L[e * 12 + j], ctx[j], acc);
      const float seq_e = ce[c * 12 + e] + pe[n * 12 + e] + val;
      x1[e] = seq_e + acc;
    }

    float mu = 0.f;
#pragma unroll
    for (int e = 0; e < 12; ++e) mu += x1[e];
    mu *= (1.0f / 12.0f);
    float var = 0.f;
#pragma unroll
    for (int e = 0; e < 12; ++e) { const float d = x1[e] - mu; var = fmaf(d, d, var); }
    var *= (1.0f / 12.0f);
    float rs = rsqrtf(var + 1e-5f);
    float h1[12];
#pragma unroll
    for (int e = 0; e < 12; ++e) h1[e] = (x1[e] - mu) * rs * L[156 + e] + L[168 + e];

    float f[24];
#pragma unroll
    for (int r = 0; r < 24; ++r) {
      float acc = L[468 + r];
#pragma unroll
      for (int e = 0; e < 12; ++e) acc = fmaf(L[180 + r * 12 + e], h1[e], acc);
      f[r] = fmaxf(acc, 0.f);
    }
    float x2[12];
#pragma unroll
    for (int e = 0; e < 12; ++e) {
      float acc = L[780 + e];
#pragma unroll
      for (int r = 0; r < 24; ++r) acc = fmaf(L[492 + e * 24 + r], f[r], acc);
      x2[e] = h1[e] + acc;
    }

    mu = 0.f;
#pragma unroll
    for (int e = 0; e < 12; ++e) mu += x2[e];
    mu *= (1.0f / 12.0f);
    var = 0.f;
#pragma unroll
    for (int e = 0; e < 12; ++e) { const float d = x2[e] - mu; var = fmaf(d, d, var); }
    var *= (1.0f / 12.0f);
    rs = rsqrtf(var + 1e-5f);

    float pv = linb[0];
#pragma unroll
    for (int e = 0; e < 12; ++e) {
      const float h2v = (x2[e] - mu) * rs * L[792 + e] + L[804 + e];
      pv = fmaf(L[816 + e], h2v, pv);
    }
    pvs[tid] = pv;                       // pvs[n*9 + p]
  }
  __syncthreads();

  if (tid < 25) {
    const int hh = tid / 5, ww = tid % 5;
    float sum = 0.f;
#pragma unroll
    for (int i = 0; i < 3; ++i) {
      const int hi = hh - i;
      if (hi < 0 || hi > 2) continue;
#pragma unroll
      for (int j = 0; j < 3; ++j) {
        const int wj = ww - j;
        if (wj < 0 || wj > 2) continue;
        sum += pvs[(hi * 3 + wj) * 9 + (i * 3 + j)];
      }
    }
    out[bc * 25 + tid] = sum;
  }
}

extern "C" void kernel_launch(void* const* d_in, const int* in_sizes, int n_in,
                              void* d_out, int out_size, void* d_ws, size_t ws_size,
                              hipStream_t stream) {
  const float* x    = (const float*)d_in[0];
  const float* ce   = (const float*)d_in[1];
  const float* pe   = (const float*)d_in[2];
  const float* ipw  = (const float*)d_in[3];
  const float* ipb  = (const float*)d_in[4];
  const float* opw  = (const float*)d_in[5];
  const float* opb  = (const float*)d_in[6];
  const float* ln1w = (const float*)d_in[7];
  const float* ln1b = (const float*)d_in[8];
  const float* f1w  = (const float*)d_in[9];
  const float* f1b  = (const float*)d_in[10];
  const float* f2w  = (const float*)d_in[11];
  const float* f2b  = (const float*)d_in[12];
  const float* ln2w = (const float*)d_in[13];
  const float* ln2b = (const float*)d_in[14];
  const float* linw = (const float*)d_in[15];
  const float* linb = (const float*)d_in[16];

  // ws layout (bytes): part [0, 36*3*2304*16 = 3981312)
  float4* part = (float4*)d_ws;

  k2_fused<<<36 * SCH * TSPLIT, 512, 0, stream>>>(x, ce, pe, ipw, ipb, part);
  k3_mlp_fold<<<256, 128, 0, stream>>>(part, x, ce, pe, opw, opb, ln1w, ln1b,
                                       f1w, f1b, f2w, f2b, ln2w, ln2b, linw,
                                       linb, (float*)d_out);
}

// Round 12
// 39.864 us; speedup vs baseline: 1.5440x; 1.5440x over previous
//
#include <hip/hip_runtime.h>
#include <hip/hip_bf16.h>
#include <math.h>

// ---- problem constants ----
#define SS 2304       // S = B*C*K*K
#define QSCALE 0.8329506128860126f  // log2(e)/sqrt(3)
#define TSPLIT 3
#define TCH 768       // SS / TSPLIT
#define SCH 9         // s-chunks of 256 rows
// grid = 36*9*3 = 972 blocks x 8 waves: single co-resident pass (<=1024)

#if defined(__has_builtin)
#if __has_builtin(__builtin_amdgcn_exp2f)
#define EXP2(x) __builtin_amdgcn_exp2f(x)
#endif
#endif
#ifndef EXP2
#define EXP2(x) exp2f(x)
#endif

// LDS layout (ushort idx):
//   K   [0,    3072)  768 tok * 4
//   V^T [3072, 6176)  4 rows, stride 776 (768 + 8 pad)
//   Q   [6176, 7200)  256 rows * 4
//   fw  [7200, 8994)  897 floats: ce+pe_n [0,768) | Wq/Wk/Wv [780,888) | b [888,897)
#define LK 0
#define LV 3072
#define LVS 776
#define LQ 6176
#define LF 7200

typedef short s8v __attribute__((ext_vector_type(8)));
typedef float f32x16 __attribute__((ext_vector_type(16)));

static __device__ __forceinline__ unsigned short f2b(float f) {
  __hip_bfloat16 h = __float2bfloat16(f);
  return __builtin_bit_cast(unsigned short, h);
}

// ============================================================
// K2': fused embed+QKV+flash-attention partials.
// block = (nh, schunk of 256 s, tc of 768 t); 972 blocks x 512 thr.
// part[(nh*TSPLIT+tc)*SS + s] = float4(o0,o1,o2,sum_exp) unnormalized.
// NOTE (R11 lesson): keep exp on the trans pipe (v_exp_f32). A packed-VALU
// polynomial exp2 regressed 39.8->61.5us: trans overlaps other waves' VALU
// issue, so moving exp onto the VALU port inflated the contended resource.
// ============================================================
__global__ __launch_bounds__(512) void k2_fused(
    const float* __restrict__ x, const float* __restrict__ ce,
    const float* __restrict__ pe, const float* __restrict__ ipw,
    const float* __restrict__ ipb, float4* __restrict__ part) {
  __shared__ __align__(16) unsigned short lds[8994];
  float* fw = (float*)(lds + LF);       // byte 14400, 16B aligned
  const int tid = threadIdx.x;
  const int tc = blockIdx.x % TSPLIT;
  const int schunk = (blockIdx.x / TSPLIT) % SCH;
  const int nh = blockIdx.x / (TSPLIT * SCH);
  const int n = nh >> 2, hh = nh & 3;
  const int t0 = tc * TCH;

  // ---- stage weights: ce+pe[n] folded, head-sliced W/b ----
  for (int i = tid; i < 768; i += 512) {
    const int e = i - (i / 12) * 12;
    fw[i] = ce[i] + pe[n * 12 + e];
  }
  if (tid < 108) {                      // Wq 780..816 | Wk 816..852 | Wv 852..888
    const int grp = tid / 36, idx = tid % 36;
    fw[780 + tid] = ipw[(grp * 12 + hh * 3 + idx / 12) * 12 + idx % 12];
  }
  if (tid >= 128 && tid < 137) {        // bq 888 | bk 891 | bv 894
    const int j = tid - 128;
    fw[888 + j] = ipb[(j / 3) * 12 + hh * 3 + (j % 3)];
  }
  __syncthreads();

  // ---- embed K/V for this block's 768 tokens ----
  for (int tl = tid; tl < TCH; tl += 512) {
    const int tg = t0 + tl;
    const int pp = tg % 9, c = (tg / 9) % 64, b = tg / 576;
    const float val =
        x[((b * 64 + c) * 5 + (pp / 3 + n / 3)) * 5 + (pp % 3 + n % 3)];
    float sq[12];
#pragma unroll
    for (int e = 0; e < 12; ++e) sq[e] = fw[c * 12 + e] + val;
    float kd[3], vd[3];
#pragma unroll
    for (int d = 0; d < 3; ++d) {
      float a1 = fw[891 + d], a2 = fw[894 + d];
#pragma unroll
      for (int e = 0; e < 12; ++e) {
        a1 = fmaf(fw[816 + d * 12 + e], sq[e], a1);   // k
        a2 = fmaf(fw[852 + d * 12 + e], sq[e], a2);   // v
      }
      kd[d] = a1; vd[d] = a2;
    }
    ushort4 kk;
    kk.x = f2b(kd[0]); kk.y = f2b(kd[1]); kk.z = f2b(kd[2]); kk.w = 0;
    *(ushort4*)(lds + LK + tl * 4) = kk;
    lds[LV + 0 * LVS + tl] = f2b(vd[0]);
    lds[LV + 1 * LVS + tl] = f2b(vd[1]);
    lds[LV + 2 * LVS + tl] = f2b(vd[2]);
    lds[LV + 3 * LVS + tl] = 0x3F80;    // ones row -> sum_exp in acc[3]
  }

  // ---- embed Q for this block's 256 s-rows ----
  if (tid < 256) {
    const int s = schunk * 256 + tid;
    const int pp = s % 9, c = (s / 9) % 64, b = s / 576;
    const float val =
        x[((b * 64 + c) * 5 + (pp / 3 + n / 3)) * 5 + (pp % 3 + n % 3)];
    float sq[12];
#pragma unroll
    for (int e = 0; e < 12; ++e) sq[e] = fw[c * 12 + e] + val;
    float qd[3];
#pragma unroll
    for (int d = 0; d < 3; ++d) {
      float a = fw[888 + d];
#pragma unroll
      for (int e = 0; e < 12; ++e) a = fmaf(fw[780 + d * 12 + e], sq[e], a);
      qd[d] = a * QSCALE;
    }
    ushort4 qq;
    qq.x = f2b(qd[0]); qq.y = f2b(qd[1]); qq.z = f2b(qd[2]); qq.w = 0;
    *(ushort4*)(lds + LQ + tid * 4) = qq;
  }
  __syncthreads();

  // ---- MFMA flash attention over 24 t-tiles ----
  const int lane = tid & 63;
  const int wv = tid >> 6;              // 0..7
  const int h = lane >> 5;
  const int sl = lane & 31;
  const int s0 = schunk * 256 + wv * 32;

  union F { s8v v; unsigned int u[4]; };

  F fq;
  {
    const uint2 qw = *(const uint2*)(lds + LQ + (wv * 32 + sl) * 4);
    fq.u[0] = h ? 0u : qw.x;
    fq.u[1] = h ? 0u : qw.y;
    fq.u[2] = 0u;
    fq.u[3] = 0u;
  }

  // static per-lane bases; t-offsets compile-time (full unroll)
  const int kbase = LK + sl * 4;                       // h=1: dup read (x0 weight)
  const int vbase = LV + (sl & 3) * LVS + h * 8;       // rows>=4 -> unread acc rows

  const f32x16 kz = {};
  f32x16 acc = {};
#pragma unroll
  for (int t = 0; t < TCH / 32; ++t) {
    F fa;
    const uint2 kw = *(const uint2*)(lds + kbase + t * 128);
    fa.u[0] = kw.x; fa.u[1] = kw.y; fa.u[2] = 0u; fa.u[3] = 0u;
    f32x16 sT = __builtin_amdgcn_mfma_f32_32x32x16_bf16(fa.v, fq.v, kz, 0, 0, 0);

    unsigned int c0, c1, c2, c3, d0, d1, d2, d3;
    {
      const float p0 = EXP2(sT[0]), p1 = EXP2(sT[1]), p2 = EXP2(sT[2]),
                  p3 = EXP2(sT[3]), p4 = EXP2(sT[4]), p5 = EXP2(sT[5]),
                  p6 = EXP2(sT[6]), p7 = EXP2(sT[7]);
      asm("v_cvt_pk_bf16_f32 %0, %1, %2" : "=v"(c0) : "v"(p0), "v"(p1));
      asm("v_cvt_pk_bf16_f32 %0, %1, %2" : "=v"(c1) : "v"(p2), "v"(p3));
      asm("v_cvt_pk_bf16_f32 %0, %1, %2" : "=v"(c2) : "v"(p4), "v"(p5));
      asm("v_cvt_pk_bf16_f32 %0, %1, %2" : "=v"(c3) : "v"(p6), "v"(p7));
    }
    {
      const float p8 = EXP2(sT[8]), p9 = EXP2(sT[9]), pa = EXP2(sT[10]),
                  pb = EXP2(sT[11]), pc = EXP2(sT[12]), pd = EXP2(sT[13]),
                  pe2 = EXP2(sT[14]), pf = EXP2(sT[15]);
      asm("v_cvt_pk_bf16_f32 %0, %1, %2" : "=v"(d0) : "v"(p8), "v"(p9));
      asm("v_cvt_pk_bf16_f32 %0, %1, %2" : "=v"(d1) : "v"(pa), "v"(pb));
      asm("v_cvt_pk_bf16_f32 %0, %1, %2" : "=v"(d2) : "v"(pc), "v"(pd));
      asm("v_cvt_pk_bf16_f32 %0, %1, %2" : "=v"(d3) : "v"(pe2), "v"(pf));
    }
    asm("v_permlane32_swap_b32 %0, %1" : "+v"(c0), "+v"(c2));
    asm("v_permlane32_swap_b32 %0, %1" : "+v"(c1), "+v"(c3));
    asm("v_permlane32_swap_b32 %0, %1" : "+v"(d0), "+v"(d2));
    asm("v_permlane32_swap_b32 %0, %1" : "+v"(d1), "+v"(d3));
    F pb0; pb0.u[0] = c0; pb0.u[1] = c1; pb0.u[2] = c2; pb0.u[3] = c3;
    F pb1; pb1.u[0] = d0; pb1.u[1] = d1; pb1.u[2] = d2; pb1.u[3] = d3;

    F fv0, fv1;
    *(uint4*)fv0.u = *(const uint4*)(lds + vbase + t * 32);
    *(uint4*)fv1.u = *(const uint4*)(lds + vbase + t * 32 + 16);
    acc = __builtin_amdgcn_mfma_f32_32x32x16_bf16(fv0.v, pb0.v, acc, 0, 0, 0);
    acc = __builtin_amdgcn_mfma_f32_32x32x16_bf16(fv1.v, pb1.v, acc, 0, 0, 0);
  }

  if (h == 0) {
    part[((size_t)(nh * TSPLIT + tc)) * SS + s0 + sl] =
        make_float4(acc[0], acc[1], acc[2], acc[3]);
  }
}

// ============================================================
// K3: combine partials -> ctx; out_proj; +seq; LN1; FF; LN2; linear; FOLD.
// block = one (b,c) pair: 81 tokens, 128 threads; 256 blocks.
// ============================================================
__global__ __launch_bounds__(128) void k3_mlp_fold(
    const float4* __restrict__ part, const float* __restrict__ x,
    const float* __restrict__ ce, const float* __restrict__ pe,
    const float* __restrict__ opw, const float* __restrict__ opb,
    const float* __restrict__ ln1w, const float* __restrict__ ln1b,
    const float* __restrict__ f1w, const float* __restrict__ f1b,
    const float* __restrict__ f2w, const float* __restrict__ f2b,
    const float* __restrict__ ln2w, const float* __restrict__ ln2b,
    const float* __restrict__ linw, const float* __restrict__ linb,
    float* __restrict__ out) {
  __shared__ float L[828];
  __shared__ float pvs[81];
  const int tid = threadIdx.x;
  for (int i = tid; i < 144; i += 128) L[i] = opw[i];
  for (int i = tid; i < 288; i += 128) {
    L[180 + i] = f1w[i];
    L[492 + i] = f2w[i];
  }
  if (tid < 12) {
    L[144 + tid] = opb[tid];
    L[156 + tid] = ln1w[tid];
    L[168 + tid] = ln1b[tid];
    L[780 + tid] = f2b[tid];
    L[792 + tid] = ln2w[tid];
    L[804 + tid] = ln2b[tid];
    L[816 + tid] = linw[tid];
  }
  if (tid < 24) L[468 + tid] = f1b[tid];
  __syncthreads();

  const int bc = blockIdx.x;             // b*64 + c
  const int c = bc & 63;

  if (tid < 81) {
    const int n = tid / 9;
    const int p = tid % 9;
    const int s = bc * 9 + p;
    const int pi = p / 3, pj = p % 3;
    const int hi = n / 3, wj = n % 3;
    const float val = x[(bc * 5 + (pi + hi)) * 5 + (pj + wj)];

    float ctx[12];
#pragma unroll
    for (int h = 0; h < 4; ++h) {
      const float4* pp = part + ((size_t)((n * 4 + h) * TSPLIT)) * SS + s;
      float l = 0.f, a0 = 0.f, a1 = 0.f, a2 = 0.f;
#pragma unroll
      for (int t = 0; t < TSPLIT; ++t) {
        const float4 v = pp[(size_t)t * SS];
        a0 += v.x; a1 += v.y; a2 += v.z; l += v.w;
      }
      const float rl = 1.0f / l;
      ctx[h * 3 + 0] = a0 * rl;
      ctx[h * 3 + 1] = a1 * rl;
      ctx[h * 3 + 2] = a2 * rl;
    }

    float x1[12];
#pragma unroll
    for (int e = 0; e < 12; ++e) {
      float acc = L[144 + e];
#pragma unroll
      for (int j = 0; j < 12; ++j) acc = fmaf(L[e * 12 + j], ctx[j], acc);
      const float seq_e = ce[c * 12 + e] + pe[n * 12 + e] + val;
      x1[e] = seq_e + acc;
    }

    float mu = 0.f;
#pragma unroll
    for (int e = 0; e < 12; ++e) mu += x1[e];
    mu *= (1.0f / 12.0f);
    float var = 0.f;
#pragma unroll
    for (int e = 0; e < 12; ++e) { const float d = x1[e] - mu; var = fmaf(d, d, var); }
    var *= (1.0f / 12.0f);
    float rs = rsqrtf(var + 1e-5f);
    float h1[12];
#pragma unroll
    for (int e = 0; e < 12; ++e) h1[e] = (x1[e] - mu) * rs * L[156 + e] + L[168 + e];

    float f[24];
#pragma unroll
    for (int r = 0; r < 24; ++r) {
      float acc = L[468 + r];
#pragma unroll
      for (int e = 0; e < 12; ++e) acc = fmaf(L[180 + r * 12 + e], h1[e], acc);
      f[r] = fmaxf(acc, 0.f);
    }
    float x2[12];
#pragma unroll
    for (int e = 0; e < 12; ++e) {
      float acc = L[780 + e];
#pragma unroll
      for (int r = 0; r < 24; ++r) acc = fmaf(L[492 + e * 24 + r], f[r], acc);
      x2[e] = h1[e] + acc;
    }

    mu = 0.f;
#pragma unroll
    for (int e = 0; e < 12; ++e) mu += x2[e];
    mu *= (1.0f / 12.0f);
    var = 0.f;
#pragma unroll
    for (int e = 0; e < 12; ++e) { const float d = x2[e] - mu; var = fmaf(d, d, var); }
    var *= (1.0f / 12.0f);
    rs = rsqrtf(var + 1e-5f);

    float pv = linb[0];
#pragma unroll
    for (int e = 0; e < 12; ++e) {
      const float h2v = (x2[e] - mu) * rs * L[792 + e] + L[804 + e];
      pv = fmaf(L[816 + e], h2v, pv);
    }
    pvs[tid] = pv;                       // pvs[n*9 + p]
  }
  __syncthreads();

  if (tid < 25) {
    const int hh = tid / 5, ww = tid % 5;
    float sum = 0.f;
#pragma unroll
    for (int i = 0; i < 3; ++i) {
      const int hi = hh - i;
      if (hi < 0 || hi > 2) continue;
#pragma unroll
      for (int j = 0; j < 3; ++j) {
        const int wj = ww - j;
        if (wj < 0 || wj > 2) continue;
        sum += pvs[(hi * 3 + wj) * 9 + (i * 3 + j)];
      }
    }
    out[bc * 25 + tid] = sum;
  }
}

extern "C" void kernel_launch(void* const* d_in, const int* in_sizes, int n_in,
                              void* d_out, int out_size, void* d_ws, size_t ws_size,
                              hipStream_t stream) {
  const float* x    = (const float*)d_in[0];
  const float* ce   = (const float*)d_in[1];
  const float* pe   = (const float*)d_in[2];
  const float* ipw  = (const float*)d_in[3];
  const float* ipb  = (const float*)d_in[4];
  const float* opw  = (const float*)d_in[5];
  const float* opb  = (const float*)d_in[6];
  const float* ln1w = (const float*)d_in[7];
  const float* ln1b = (const float*)d_in[8];
  const float* f1w  = (const float*)d_in[9];
  const float* f1b  = (const float*)d_in[10];
  const float* f2w  = (const float*)d_in[11];
  const float* f2b  = (const float*)d_in[12];
  const float* ln2w = (const float*)d_in[13];
  const float* ln2b = (const float*)d_in[14];
  const float* linw = (const float*)d_in[15];
  const float* linb = (const float*)d_in[16];

  // ws layout (bytes): part [0, 36*3*2304*16 = 3981312)
  float4* part = (float4*)d_ws;

  k2_fused<<<36 * SCH * TSPLIT, 512, 0, stream>>>(x, ce, pe, ipw, ipb, part);
  k3_mlp_fold<<<256, 128, 0, stream>>>(part, x, ce, pe, opw, opb, ln1w, ln1b,
                                       f1w, f1b, f2w, f2b, ln2w, ln2b, linw,
                                       linb, (float*)d_out);
}